// Round 2
// baseline (79.622 us; speedup 1.0000x reference)
//
#include <hip/hip_runtime.h>
#include <math.h>

#define GMM_D 32
#define GMM_K 16
#define PTS_PER_THREAD 2
#define BLOCK 256

// out[n][k] = alpha_k - LSE(alpha) - sum_d log(std_kd) - (D/2)*log(2*pi)
//             - 0.5 * sum_d min( ((x_nd - mu_kd)/std_kd)^2 , 20 )
// with std = max(std, 0.1).
// Inner trick: min(z^2, 20) == min(|z|, sqrt(20))^2  (monotone; |.| is a free
// VOP3 input modifier, so per element: v_fma, v_min(abs), v_fma = 3 VALU ops).
#define CLAMP_R 4.47213595499957939f  // sqrt(20)

__global__ __launch_bounds__(BLOCK) void gmm_kernel(
    const float* __restrict__ x,
    const float* __restrict__ mu,
    const float* __restrict__ stdv,
    const float* __restrict__ alpha,
    float* __restrict__ out, int N)
{
    // quad per dim-pair: (inv0, -mu0*inv0, inv1, -mu1*inv1) -> one ds_read_b128
    __shared__ float4 cpair[GMM_K * GMM_D / 2];
    __shared__ float ck[GMM_K];
    __shared__ float lsums[GMM_K * GMM_D];

    const int tid = threadIdx.x;

    // ---- per-block constant setup (512 entries, overlapped, cheap) ----
    for (int i = tid; i < GMM_K * GMM_D / 2; i += BLOCK) {
        const int e0 = 2 * i, e1 = 2 * i + 1;
        const float s0 = fmaxf(stdv[e0], 0.1f);
        const float s1 = fmaxf(stdv[e1], 0.1f);
        const float is0 = 1.0f / s0;
        const float is1 = 1.0f / s1;
        cpair[i] = make_float4(is0, -mu[e0] * is0, is1, -mu[e1] * is1);
        lsums[e0] = logf(s0);
        lsums[e1] = logf(s1);
    }
    __syncthreads();
    if (tid < GMM_K) {
        float m = alpha[0];
        for (int k = 1; k < GMM_K; ++k) m = fmaxf(m, alpha[k]);
        float se = 0.0f;
        for (int k = 0; k < GMM_K; ++k) se += expf(alpha[k] - m);
        const float lse = m + logf(se);
        float s = 0.0f;
        for (int d = 0; d < GMM_D; ++d) s += lsums[tid * GMM_D + d];
        // (D/2)*log(2*pi) = 16 * 1.8378770664093453
        ck[tid] = alpha[tid] - lse - s - 29.406033062549525f;
    }
    __syncthreads();

    // ---- 2 points per thread: constants quad read once, used twice ----
    const int n0 = blockIdx.x * (BLOCK * PTS_PER_THREAD) + tid;
    const int n1 = n0 + BLOCK;

    float xr0[GMM_D], xr1[GMM_D];
    const bool v0 = (n0 < N), v1 = (n1 < N);
    if (v0) {
        const float4* xv = reinterpret_cast<const float4*>(x + (size_t)n0 * GMM_D);
#pragma unroll
        for (int i = 0; i < GMM_D / 4; ++i) {
            const float4 v = xv[i];
            xr0[4 * i] = v.x; xr0[4 * i + 1] = v.y; xr0[4 * i + 2] = v.z; xr0[4 * i + 3] = v.w;
        }
    }
    if (v1) {
        const float4* xv = reinterpret_cast<const float4*>(x + (size_t)n1 * GMM_D);
#pragma unroll
        for (int i = 0; i < GMM_D / 4; ++i) {
            const float4 v = xv[i];
            xr1[4 * i] = v.x; xr1[4 * i + 1] = v.y; xr1[4 * i + 2] = v.z; xr1[4 * i + 3] = v.w;
        }
    }

    float4* ov0 = reinterpret_cast<float4*>(out + (size_t)n0 * GMM_K);
    float4* ov1 = reinterpret_cast<float4*>(out + (size_t)n1 * GMM_K);

#pragma unroll
    for (int kq = 0; kq < GMM_K / 4; ++kq) {
        float a0[4], a1[4];
#pragma unroll
        for (int j = 0; j < 4; ++j) { a0[j] = 0.f; a1[j] = 0.f; }
#pragma unroll
        for (int h = 0; h < GMM_D / 2; ++h) {
            const float x00 = xr0[2 * h], x01 = xr0[2 * h + 1];
            const float x10 = xr1[2 * h], x11 = xr1[2 * h + 1];
#pragma unroll
            for (int j = 0; j < 4; ++j) {
                const float4 c = cpair[(4 * kq + j) * (GMM_D / 2) + h];
                float z, t;
                z = fmaf(x00, c.x, c.y); t = fminf(fabsf(z), CLAMP_R); a0[j] = fmaf(t, t, a0[j]);
                z = fmaf(x01, c.z, c.w); t = fminf(fabsf(z), CLAMP_R); a0[j] = fmaf(t, t, a0[j]);
                z = fmaf(x10, c.x, c.y); t = fminf(fabsf(z), CLAMP_R); a1[j] = fmaf(t, t, a1[j]);
                z = fmaf(x11, c.z, c.w); t = fminf(fabsf(z), CLAMP_R); a1[j] = fmaf(t, t, a1[j]);
            }
        }
        float4 r;
        if (v0) {
            r.x = fmaf(-0.5f, a0[0], ck[4 * kq + 0]);
            r.y = fmaf(-0.5f, a0[1], ck[4 * kq + 1]);
            r.z = fmaf(-0.5f, a0[2], ck[4 * kq + 2]);
            r.w = fmaf(-0.5f, a0[3], ck[4 * kq + 3]);
            ov0[kq] = r;
        }
        if (v1) {
            r.x = fmaf(-0.5f, a1[0], ck[4 * kq + 0]);
            r.y = fmaf(-0.5f, a1[1], ck[4 * kq + 1]);
            r.z = fmaf(-0.5f, a1[2], ck[4 * kq + 2]);
            r.w = fmaf(-0.5f, a1[3], ck[4 * kq + 3]);
            ov1[kq] = r;
        }
    }
}

extern "C" void kernel_launch(void* const* d_in, const int* in_sizes, int n_in,
                              void* d_out, int out_size, void* d_ws, size_t ws_size,
                              hipStream_t stream) {
    const float* x     = (const float*)d_in[0];
    const float* mu    = (const float*)d_in[1];
    const float* stdv  = (const float*)d_in[2];
    const float* alpha = (const float*)d_in[3];
    float* out = (float*)d_out;

    const int N = in_sizes[0] / GMM_D;                       // 131072
    const int grid = (N + BLOCK * PTS_PER_THREAD - 1) / (BLOCK * PTS_PER_THREAD);  // 256
    gmm_kernel<<<grid, BLOCK, 0, stream>>>(x, mu, stdv, alpha, out, N);
}